// Round 4
// baseline (1705.499 us; speedup 1.0000x reference)
//
#include <hip/hip_runtime.h>
#include <math.h>

// SelfContact: v2v_min[b,j] = min_i ( geomask[i,j] ? sq[b,i]+sq[b,j]-2*dot(v[b,i],v[b,j]) : inf )
// in_contact[b,j] = v2v_min[b,j] < 0.02^2
//
// Numerics mirror the NumPy fp32 reference exactly: separate mul/add (no FMA)
// via __fmul_rn/__fadd_rn/__fsub_rn; 2*dot folded into pre-doubled column
// coords (x2 scaling commutes with round-to-nearest — bitwise equal).
//
// R3: symmetry (upper-triangle tiles; col-min in regs, row-min via DPP wave
//     reduce). R4: the kernel is issue/latency-bound, not BW-bound ->
//     NC=8 cols/thread (halves per-dword DPP/LDS/loop overhead),
//     software-pipelined double-buffered mask loads (16 in flight),
//     perfectly balanced persistent grid: 1288 uniform 32x2048 tiles,
//     644 blocks x exactly 2 tiles, launch_bounds(256,3) for co-residency.

#define NV   10475
#define NB   2
#define BLK  256
#define NC   8                          // columns per thread
#define CPB  (BLK * NC)                 // 2048 columns per tile
#define JB   ((NV + CPB - 1) / CPB)     // 6 column tiles
#define CH   32                         // rows per tile
#define RCT  ((NV + CH - 1) / CH)       // 328 row chunks
#define NTILES 1288                     // sum over jb of (jmax/CH + 1)
#define NBLK   644                      // each block does exactly 2 tiles

__device__ __forceinline__ float sq_nofma(float x, float y, float z) {
    return __fadd_rn(__fadd_rn(__fmul_rn(x, x), __fmul_rn(y, y)), __fmul_rn(z, z));
}

template <int CTRL>
__device__ __forceinline__ float dppmin(float v) {
    int s = __builtin_amdgcn_update_dpp(__float_as_int(v), __float_as_int(v),
                                        CTRL, 0xF, 0xF, false);
    return fminf(v, __int_as_float(s));
}

// Full-wave (64-lane) min; result valid in lane 63. All lanes active.
__device__ __forceinline__ float wave_min_to_lane63(float v) {
    v = dppmin<0x111>(v);  // row_shr:1
    v = dppmin<0x112>(v);  // row_shr:2
    v = dppmin<0x114>(v);  // row_shr:4
    v = dppmin<0x118>(v);  // row_shr:8
    v = dppmin<0x142>(v);  // row_bcast:15
    v = dppmin<0x143>(v);  // row_bcast:31 -> lane 63 = wave min
    return v;
}

__global__ __launch_bounds__(BLK, 3) void sc_partial(
    const float* __restrict__ verts,    // [NB, NV, 3]
    const int*   __restrict__ gmask,    // [NV, NV]
    float*       __restrict__ colpart,  // [RCT, NB, NV]
    float*       __restrict__ rowpart)  // [JB, NB, NV]
{
    __shared__ float4 sv[CH * NB];      // staged row verts: (x,y,z,sq) per batch
    __shared__ float  rmin[CH][4][NB];  // per-row per-wave row-min

    const int tid = threadIdx.x;
    const int wv  = tid >> 6;

    for (int t = blockIdx.x; t < NTILES; t += NBLK) {
        int jb, rcb;
        if      (t <  64) { jb = 0; rcb = t;       }
        else if (t < 192) { jb = 1; rcb = t -  64; }
        else if (t < 384) { jb = 2; rcb = t - 192; }
        else if (t < 640) { jb = 3; rcb = t - 384; }
        else if (t < 960) { jb = 4; rcb = t - 640; }
        else              { jb = 5; rcb = t - 960; }

        const int j0    = jb * CPB;
        const int jmax  = (j0 + CPB - 1 < NV - 1) ? (j0 + CPB - 1) : (NV - 1);
        const int r0    = rcb * CH;
        const int nrows = (CH < jmax + 1 - r0) ? CH : (jmax + 1 - r0);
        const int nr4   = (nrows + 3) & ~3;

        __syncthreads();   // sv/rmin reuse across this block's tiles

        // ---- stage row vertices (+sq), rows clamped to jmax (benign dups) ----
        for (int k = tid; k < nr4 * NB; k += BLK) {
            int rr = k >> 1, b = k & 1;
            int row = r0 + rr; if (row > jmax) row = jmax;
            const float* vp = verts + ((size_t)b * NV + row) * 3;
            float x = vp[0], y = vp[1], z = vp[2];
            sv[rr * NB + b] = make_float4(x, y, z, sq_nofma(x, y, z));
        }
        __syncthreads();

        // ---- my NC columns (stride-BLK so every mask load is coalesced) ----
        int  cols[NC];
        bool cval[NC];
        float cx2[NB][NC], cy2[NB][NC], cz2[NB][NC], cs[NB][NC];
#pragma unroll
        for (int c = 0; c < NC; ++c) {
            int col = j0 + tid + c * BLK;
            cval[c] = (col < NV);
            cols[c] = cval[c] ? col : (NV - 1);
#pragma unroll
            for (int b = 0; b < NB; ++b) {
                const float* vp = verts + ((size_t)b * NV + cols[c]) * 3;
                float x = vp[0], y = vp[1], z = vp[2];
                cx2[b][c] = __fmul_rn(2.0f, x);
                cy2[b][c] = __fmul_rn(2.0f, y);
                cz2[b][c] = __fmul_rn(2.0f, z);
                cs[b][c]  = sq_nofma(x, y, z);
            }
        }

        float mn[NB][NC];
#pragma unroll
        for (int b = 0; b < NB; ++b)
#pragma unroll
            for (int c = 0; c < NC; ++c) mn[b][c] = __builtin_inff();

        // Load a PAIR of rows' masks (local rows LR, LR+1; clamped to jmax)
#define LOADP(LR, MK)                                                          \
        {                                                                      \
            int rA = r0 + (LR);     if (rA > jmax) rA = jmax;                  \
            int rB = r0 + (LR) + 1; if (rB > jmax) rB = jmax;                  \
            const int* gA = gmask + (size_t)rA * NV;                           \
            const int* gB = gmask + (size_t)rB * NV;                           \
            _Pragma("unroll")                                                  \
            for (int c = 0; c < NC; ++c) MK[0][c] = gA[cols[c]];               \
            _Pragma("unroll")                                                  \
            for (int c = 0; c < NC; ++c) MK[1][c] = gB[cols[c]];               \
        }

#define ROW_BODY(LR, MKR)                                                      \
        {                                                                      \
            int lrr = (LR);                                                    \
            float4 a0 = sv[lrr * NB + 0];                                      \
            float4 a1 = sv[lrr * NB + 1];                                      \
            float rf0 = __builtin_inff(), rf1 = __builtin_inff();              \
            float t0[NC], t1[NC];                                              \
            _Pragma("unroll")                                                  \
            for (int c = 0; c < NC; ++c) {                                     \
                bool act = cval[c] && (MKR[c] != 0);                           \
                float d0 = __fadd_rn(__fadd_rn(__fmul_rn(a0.x, cx2[0][c]),     \
                                               __fmul_rn(a0.y, cy2[0][c])),   \
                                     __fmul_rn(a0.z, cz2[0][c]));              \
                float v0 = __fsub_rn(__fadd_rn(a0.w, cs[0][c]), d0);           \
                t0[c] = act ? v0 : __builtin_inff();                           \
                mn[0][c] = fminf(mn[0][c], t0[c]);                             \
                float d1 = __fadd_rn(__fadd_rn(__fmul_rn(a1.x, cx2[1][c]),     \
                                               __fmul_rn(a1.y, cy2[1][c])),   \
                                     __fmul_rn(a1.z, cz2[1][c]));              \
                float v1 = __fsub_rn(__fadd_rn(a1.w, cs[1][c]), d1);           \
                t1[c] = act ? v1 : __builtin_inff();                           \
                mn[1][c] = fminf(mn[1][c], t1[c]);                             \
            }                                                                  \
            _Pragma("unroll")                                                  \
            for (int c = 0; c < NC; c += 2) {                                  \
                rf0 = fminf(rf0, fminf(t0[c], t0[c + 1]));  /* v_min3 */       \
                rf1 = fminf(rf1, fminf(t1[c], t1[c + 1]));                     \
            }                                                                  \
            rf0 = wave_min_to_lane63(rf0);                                     \
            rf1 = wave_min_to_lane63(rf1);                                     \
            if ((tid & 63) == 63) {                                            \
                rmin[lrr][wv][0] = rf0;                                        \
                rmin[lrr][wv][1] = rf1;                                        \
            }                                                                  \
        }

        // ---- software-pipelined main loop: 4 rows/step, dbuf'd mask loads ----
        int mk0[2][NC], mk1[2][NC];
        LOADP(0, mk0);
        for (int lr = 0; lr < nr4; lr += 4) {
            LOADP(lr + 2, mk1);
            ROW_BODY(lr,     mk0[0]);
            ROW_BODY(lr + 1, mk0[1]);
            if (lr + 4 < nr4) LOADP(lr + 4, mk0);
            ROW_BODY(lr + 2, mk1[0]);
            ROW_BODY(lr + 3, mk1[1]);
        }
#undef LOADP
#undef ROW_BODY

        __syncthreads();

        // ---- row-min partials (unique writer: block of tile (jb, chunk)) ----
        for (int k = tid; k < nrows * NB; k += BLK) {
            int rr = k >> 1, b = k & 1;
            float m = fminf(fminf(rmin[rr][0][b], rmin[rr][1][b]),
                            fminf(rmin[rr][2][b], rmin[rr][3][b]));
            rowpart[((size_t)jb * NB + b) * NV + (r0 + rr)] = m;
        }

        // ---- col-min partials (unique writer: block of tile (jb, rcb)) ----
#pragma unroll
        for (int c = 0; c < NC; ++c) {
            if (cval[c]) {
                colpart[((size_t)rcb * NB + 0) * NV + cols[c]] = mn[0][c];
                colpart[((size_t)rcb * NB + 1) * NV + cols[c]] = mn[1][c];
            }
        }
    }
}

__global__ __launch_bounds__(BLK) void sc_reduce(
    const float* __restrict__ colpart,  // [RCT, NB, NV]
    const float* __restrict__ rowpart,  // [JB, NB, NV]
    float*       __restrict__ out)      // [NB*NV] mins then [NB*NV] contact
{
    int idx = blockIdx.x * BLK + threadIdx.x;
    if (idx >= NB * NV) return;
    int b = idx / NV, j = idx - b * NV;

    int jb    = j / CPB;
    int jmax  = ((jb + 1) * CPB - 1 < NV - 1) ? ((jb + 1) * CPB - 1) : (NV - 1);
    int rcmax = jmax / CH;   // exactly the chunks whose tile (jb, rcb) exists

    float m = __builtin_inff();
#pragma unroll 8
    for (int rcb = 0; rcb <= rcmax; ++rcb)
        m = fminf(m, colpart[((size_t)rcb * NB + b) * NV + j]);
#pragma unroll
    for (int jb2 = 0; jb2 < JB; ++jb2)   // rowpart[jb2][b][j] valid iff jb2 >= jb
        if (jb2 >= jb)
            m = fminf(m, rowpart[((size_t)jb2 * NB + b) * NV + j]);

    out[idx] = m;
    out[NB * NV + idx] = ((double)m < 0.02 * 0.02) ? 1.0f : 0.0f;
}

extern "C" void kernel_launch(void* const* d_in, const int* in_sizes, int n_in,
                              void* d_out, int out_size, void* d_ws, size_t ws_size,
                              hipStream_t stream) {
    const float* verts = (const float*)d_in[0];
    const int*   gmask = (const int*)d_in[1];
    float* out     = (float*)d_out;
    float* colpart = (float*)d_ws;                          // RCT*NB*NV*4 ~27.5 MB
    float* rowpart = colpart + (size_t)RCT * NB * NV;       // JB*NB*NV*4  ~0.5 MB

    sc_partial<<<NBLK, dim3(BLK), 0, stream>>>(verts, gmask, colpart, rowpart);

    int nred = (NB * NV + BLK - 1) / BLK;
    sc_reduce<<<nred, dim3(BLK), 0, stream>>>(colpart, rowpart, out);
}

// Round 5
// 587.526 us; speedup vs baseline: 2.9029x; 2.9029x over previous
//
#include <hip/hip_runtime.h>
#include <math.h>

// SelfContact: v2v_min[b,j] = min_i ( geomask[i,j] ? sq[b,i]+sq[b,j]-2*dot(v[b,i],v[b,j]) : inf )
// in_contact[b,j] = v2v_min[b,j] < 0.02^2
//
// Numerics mirror the NumPy fp32 reference exactly: separate mul/add (no FMA)
// via __fmul_rn/__fadd_rn/__fsub_rn; 2*dot folded into pre-doubled column
// coords (x2 scaling commutes with round-to-nearest — bitwise equal).
//
// R3: symmetry — upper-triangle tiles only; col-min in registers, row-min via
//     DPP wave reduce (mask traffic 439 -> ~274 MB).
// R4 FAILED: launch_bounds(256,3) capped VGPR at 84 < ~130 needed -> 2.7 GB
//     scratch spill traffic. Lesson: never cap occupancy below register need.
// R5: NC=4 footprint (no spill), NO min-occupancy clause, uniform tile grid
//     (1044 equal 64x1024 tiles, zero dead blocks), 16 mask loads batched per
//     4-row group for MLP.

#define NV   10475
#define NB   2
#define BLK  256
#define NC   4                          // columns per thread
#define CPB  (BLK * NC)                 // 1024 columns per tile
#define JB   ((NV + CPB - 1) / CPB)     // 11 column tiles
#define CH   64                         // rows per tile
#define RCT  ((NV + CH - 1) / CH)       // 164 row chunks (jb=10 spans all)
#define RU   4                          // row unroll
#define NTILES 1044                     // sum over jb of (jmax/CH + 1)

__device__ __forceinline__ float sq_nofma(float x, float y, float z) {
    return __fadd_rn(__fadd_rn(__fmul_rn(x, x), __fmul_rn(y, y)), __fmul_rn(z, z));
}

template <int CTRL>
__device__ __forceinline__ float dppmin(float v) {
    int s = __builtin_amdgcn_update_dpp(__float_as_int(v), __float_as_int(v),
                                        CTRL, 0xF, 0xF, false);
    return fminf(v, __int_as_float(s));
}

// Full-wave (64-lane) min; result valid in lane 63. All lanes active.
__device__ __forceinline__ float wave_min_to_lane63(float v) {
    v = dppmin<0x111>(v);  // row_shr:1
    v = dppmin<0x112>(v);  // row_shr:2
    v = dppmin<0x114>(v);  // row_shr:4
    v = dppmin<0x118>(v);  // row_shr:8
    v = dppmin<0x142>(v);  // row_bcast:15
    v = dppmin<0x143>(v);  // row_bcast:31 -> lane 63 = wave min
    return v;
}

__global__ __launch_bounds__(BLK) void sc_partial(
    const float* __restrict__ verts,    // [NB, NV, 3]
    const int*   __restrict__ gmask,    // [NV, NV]
    float*       __restrict__ colpart,  // [RCT, NB, NV]
    float*       __restrict__ rowpart)  // [JB, NB, NV]
{
    __shared__ float4 sv[CH * NB];      // staged row verts: (x,y,z,sq) per batch
    __shared__ float  rmin[CH][4][NB];  // per-row per-wave row-min

    const int tid = threadIdx.x;
    const int wv  = tid >> 6;

    // ---- uniform upper-triangle tile enumeration (cum tiles per jb) ----
    int t = blockIdx.x;
    int jb, rcb;
    if      (t <  16) { jb = 0;  rcb = t;       }
    else if (t <  48) { jb = 1;  rcb = t -  16; }
    else if (t <  96) { jb = 2;  rcb = t -  48; }
    else if (t < 160) { jb = 3;  rcb = t -  96; }
    else if (t < 240) { jb = 4;  rcb = t - 160; }
    else if (t < 336) { jb = 5;  rcb = t - 240; }
    else if (t < 448) { jb = 6;  rcb = t - 336; }
    else if (t < 576) { jb = 7;  rcb = t - 448; }
    else if (t < 720) { jb = 8;  rcb = t - 576; }
    else if (t < 880) { jb = 9;  rcb = t - 720; }
    else              { jb = 10; rcb = t - 880; }

    const int j0    = jb * CPB;
    const int jmax  = (j0 + CPB - 1 < NV - 1) ? (j0 + CPB - 1) : (NV - 1);
    const int r0    = rcb * CH;
    const int nrows = (CH < jmax + 1 - r0) ? CH : (jmax + 1 - r0);
    const int nr4   = (nrows + 3) & ~3;

    // ---- stage row vertices (+sq); rows past jmax clamp to jmax (benign) ----
    for (int k = tid; k < nr4 * NB; k += BLK) {
        int rr = k >> 1, b = k & 1;
        int row = r0 + rr; if (row > jmax) row = jmax;
        const float* vp = verts + ((size_t)b * NV + row) * 3;
        float x = vp[0], y = vp[1], z = vp[2];
        sv[rr * NB + b] = make_float4(x, y, z, sq_nofma(x, y, z));
    }
    __syncthreads();

    // ---- my NC columns (stride-BLK so every mask load is wave-coalesced) ----
    int  cols[NC];
    bool cval[NC];
    float cx2[NB][NC], cy2[NB][NC], cz2[NB][NC], cs[NB][NC];
#pragma unroll
    for (int c = 0; c < NC; ++c) {
        int col = j0 + tid + c * BLK;
        cval[c] = (col < NV);
        cols[c] = cval[c] ? col : (NV - 1);
#pragma unroll
        for (int b = 0; b < NB; ++b) {
            const float* vp = verts + ((size_t)b * NV + cols[c]) * 3;
            float x = vp[0], y = vp[1], z = vp[2];
            cx2[b][c] = __fmul_rn(2.0f, x);
            cy2[b][c] = __fmul_rn(2.0f, y);
            cz2[b][c] = __fmul_rn(2.0f, z);
            cs[b][c]  = sq_nofma(x, y, z);
        }
    }

    float mn[NB][NC];
#pragma unroll
    for (int b = 0; b < NB; ++b)
#pragma unroll
        for (int c = 0; c < NC; ++c) mn[b][c] = __builtin_inff();

#define ROW_BODY(LR, MKR)                                                      \
    {                                                                          \
        int lrr = (LR);                                                        \
        float4 a0 = sv[lrr * NB + 0];                                          \
        float4 a1 = sv[lrr * NB + 1];                                          \
        float rf0 = __builtin_inff(), rf1 = __builtin_inff();                  \
        _Pragma("unroll")                                                      \
        for (int c = 0; c < NC; ++c) {                                         \
            bool act = cval[c] && (MKR[c] != 0);                               \
            float d0 = __fadd_rn(__fadd_rn(__fmul_rn(a0.x, cx2[0][c]),         \
                                           __fmul_rn(a0.y, cy2[0][c])),        \
                                 __fmul_rn(a0.z, cz2[0][c]));                  \
            float v0 = __fsub_rn(__fadd_rn(a0.w, cs[0][c]), d0);               \
            float t0 = act ? v0 : __builtin_inff();                            \
            mn[0][c] = fminf(mn[0][c], t0);                                    \
            rf0      = fminf(rf0, t0);                                         \
            float d1 = __fadd_rn(__fadd_rn(__fmul_rn(a1.x, cx2[1][c]),         \
                                           __fmul_rn(a1.y, cy2[1][c])),        \
                                 __fmul_rn(a1.z, cz2[1][c]));                  \
            float v1 = __fsub_rn(__fadd_rn(a1.w, cs[1][c]), d1);               \
            float t1 = act ? v1 : __builtin_inff();                            \
            mn[1][c] = fminf(mn[1][c], t1);                                    \
            rf1      = fminf(rf1, t1);                                         \
        }                                                                      \
        rf0 = wave_min_to_lane63(rf0);                                         \
        rf1 = wave_min_to_lane63(rf1);                                         \
        if ((tid & 63) == 63) {                                                \
            rmin[lrr][wv][0] = rf0;                                            \
            rmin[lrr][wv][1] = rf1;                                            \
        }                                                                      \
    }

    // ---- main loop: RU rows/step, all 16 mask loads batched before compute ----
    for (int lr = 0; lr < nr4; lr += RU) {
        int mk[RU][NC];
#pragma unroll
        for (int r = 0; r < RU; ++r) {
            int row = r0 + lr + r; if (row > jmax) row = jmax;
            const int* grow = gmask + (size_t)row * NV;
#pragma unroll
            for (int c = 0; c < NC; ++c) mk[r][c] = grow[cols[c]];
        }
#pragma unroll
        for (int r = 0; r < RU; ++r)
            ROW_BODY(lr + r, mk[r]);
    }
#undef ROW_BODY

    __syncthreads();

    // ---- row-min partials (unique writer: tile (jb, chunk-of-row)) ----
    for (int k = tid; k < nrows * NB; k += BLK) {
        int rr = k >> 1, b = k & 1;
        float m = fminf(fminf(rmin[rr][0][b], rmin[rr][1][b]),
                        fminf(rmin[rr][2][b], rmin[rr][3][b]));
        rowpart[((size_t)jb * NB + b) * NV + (r0 + rr)] = m;
    }

    // ---- col-min partials (unique writer: tile (jb, rcb)) ----
#pragma unroll
    for (int c = 0; c < NC; ++c) {
        if (cval[c]) {
            colpart[((size_t)rcb * NB + 0) * NV + cols[c]] = mn[0][c];
            colpart[((size_t)rcb * NB + 1) * NV + cols[c]] = mn[1][c];
        }
    }
}

__global__ __launch_bounds__(BLK) void sc_reduce(
    const float* __restrict__ colpart,  // [RCT, NB, NV]
    const float* __restrict__ rowpart,  // [JB, NB, NV]
    float*       __restrict__ out)      // [NB*NV] mins then [NB*NV] contact
{
    int idx = blockIdx.x * BLK + threadIdx.x;
    if (idx >= NB * NV) return;
    int b = idx / NV, j = idx - b * NV;

    int jb    = j / CPB;
    int jmax  = ((jb + 1) * CPB - 1 < NV - 1) ? ((jb + 1) * CPB - 1) : (NV - 1);
    int rcmax = jmax / CH;   // exactly the chunks whose tile (jb, rcb) exists

    float m = __builtin_inff();
#pragma unroll 8
    for (int rcb = 0; rcb <= rcmax; ++rcb)
        m = fminf(m, colpart[((size_t)rcb * NB + b) * NV + j]);
#pragma unroll
    for (int jb2 = 0; jb2 < JB; ++jb2)   // rowpart[jb2][b][j] valid iff jb2 >= jb
        if (jb2 >= jb)
            m = fminf(m, rowpart[((size_t)jb2 * NB + b) * NV + j]);

    out[idx] = m;
    out[NB * NV + idx] = ((double)m < 0.02 * 0.02) ? 1.0f : 0.0f;
}

extern "C" void kernel_launch(void* const* d_in, const int* in_sizes, int n_in,
                              void* d_out, int out_size, void* d_ws, size_t ws_size,
                              hipStream_t stream) {
    const float* verts = (const float*)d_in[0];
    const int*   gmask = (const int*)d_in[1];
    float* out     = (float*)d_out;
    float* colpart = (float*)d_ws;                          // RCT*NB*NV*4 ~13.7 MB
    float* rowpart = colpart + (size_t)RCT * NB * NV;       // JB*NB*NV*4  ~0.9 MB

    sc_partial<<<NTILES, dim3(BLK), 0, stream>>>(verts, gmask, colpart, rowpart);

    int nred = (NB * NV + BLK - 1) / BLK;
    sc_reduce<<<nred, dim3(BLK), 0, stream>>>(colpart, rowpart, out);
}